// Round 14
// baseline (2719.929 us; speedup 1.0000x reference)
//
#include <hip/hip_runtime.h>
#include <cstdint>
#include <cstddef>

#define D_DIM   1024
#define TWO_D   2048
#define B_DIM   8
#define T_DIM   4096
#define BT_DIM  (B_DIM*T_DIM)     // 32768 rows
#define LN_EPS  1e-5f
#define NCHUNK  128
#define CLEN    (T_DIM/NCHUNK)    // 32 steps per chunk

typedef __attribute__((ext_vector_type(8))) short bf16x8;
typedef __attribute__((ext_vector_type(4))) float f32x4;

__device__ __forceinline__ float bf2f(unsigned short u){
  union { unsigned int i; float f; } c; c.i = ((unsigned int)u) << 16; return c.f;
}
__device__ __forceinline__ unsigned short f2bf(float f){
  union { float f; unsigned int i; } c; c.f = f;
  unsigned int x = c.i;
  return (unsigned short)((x + 0x7fffu + ((x >> 16) & 1u)) >> 16);
}
__device__ __forceinline__ float sigmoidf_(float x){ return 1.f/(1.f+__expf(-x)); }
__device__ __forceinline__ float siluf_(float x){ return x/(1.f+__expf(-x)); }

// ---------------- conversion kernels ----------------

__global__ void cvt_f32_bf16(const float* __restrict__ in, unsigned short* __restrict__ out, int n){
  int i = (blockIdx.x*blockDim.x + threadIdx.x)*4;
  const int stride = gridDim.x*blockDim.x*4;
  for (; i + 3 < n; i += stride){
    float4 f = *(const float4*)(in + i);
    ushort4 o; o.x=f2bf(f.x); o.y=f2bf(f.y); o.z=f2bf(f.z); o.w=f2bf(f.w);
    *(ushort4*)(out + i) = o;
  }
}

// LDS-tiled transpose: W (rows x cols, fp32) -> Wt (cols x rows, bf16).
__global__ __launch_bounds__(256) void cvt_transpose(
    const float* __restrict__ W, unsigned short* __restrict__ Wt,
    int rows, int cols)
{
  __shared__ float tile[32][33];
  const int tx = threadIdx.x & 31;
  const int ty = threadIdx.x >> 5;        // 0..7
  const int tpc = cols >> 5;
  const int bc = blockIdx.x % tpc;
  const int br = blockIdx.x / tpc;
  const int gc = bc*32 + tx;
  const int gr = br*32;
#pragma unroll
  for (int i = 0; i < 32; i += 8)
    tile[ty + i][tx] = W[(size_t)(gr + ty + i)*cols + gc];
  __syncthreads();
#pragma unroll
  for (int i = 0; i < 32; i += 8)
    Wt[(size_t)(bc*32 + ty + i)*rows + gr + tx] = f2bf(tile[tx][ty + i]);
}

// ---------------- 256x256 GEMM, BK=32, 1 phase/tile, 2 blocks/CU (R14) ----------------
// Occupancy experiment on the R12/R13 template: LDS halved to 64KB (2 parities x
// 256x32 per operand) -> 2 blocks/CU co-resident, so the m114 cross-block
// overlap can fill this block's barrier/vm-wait windows (the mechanism the
// 128KB/1-block config lacked). One phase per K-tile: {12 frag ds_reads,
// stage next tile (4 glds), 32 MFMA (compiler inserts counted lgkm waits),
// vmcnt(0), barrier}. Hazards: reads of parity p complete before tile-end
// barrier (lgkm before consuming MFMA); DMAs to p^1 landed per-wave by vm0
// before barrier -> next tile's reads/stage safe with ONE barrier.
// Literal parity indices preserved (no hidden waitcnt drains); XOR read/source
// swizzle; bijective XCD swizzle; launch_bounds(512,4) caps VGPR at 128.
template<int EPI>
__global__ __launch_bounds__(512, 4) void gemm256(
    const unsigned short* __restrict__ A,    // M x K bf16
    const unsigned short* __restrict__ Bt,   // N x K bf16
    const float* __restrict__ bias,          // N
    const float* __restrict__ resid,         // M x 1024 fp32 (EPI 1)
    unsigned short* __restrict__ outU,
    unsigned short* __restrict__ outV,
    const int K, const int nbn)
{
  __shared__ __align__(16) unsigned short sA[2][8192];   // [parity][256 rows x 32 cols]
  __shared__ __align__(16) unsigned short sB[2][8192];

#define BARRIER()   __builtin_amdgcn_s_barrier()
#define FENCE()     __builtin_amdgcn_sched_barrier(0)
#define WAIT_VM0()  do { asm volatile("s_waitcnt vmcnt(0)"); } while(0)

  const int tid  = threadIdx.x;
  const int lane = tid & 63;
  const int wv   = tid >> 6;          // 0..7
  const int wr   = wv >> 2;           // 0..1  (M half)
  const int wc   = wv & 3;            // 0..3  (N quarter)
  const int fr   = lane & 15;
  const int fq   = lane >> 4;

  // bijective XCD swizzle (nwg % 8 == 0 by construction)
  const int nwg = gridDim.x;
  const int cpx = nwg >> 3;
  const int wg  = (blockIdx.x & 7) * cpx + (blockIdx.x >> 3);
  const int bm = wg / nbn, bn = wg % nbn;

  const unsigned short* Ag = A  + (size_t)bm * 256 * K;
  const unsigned short* Bg = Bt + (size_t)bn * 256 * K;

  // staging: thread -> (row = tid>>2 [+128], 16B chunk = tid&3), LDS linear,
  // global column chunk XOR-swizzled (involution, same XOR applied on read)
  const int r0  = tid >> 2;           // rows 0..127
  const int r1  = 128 + r0;           // rows 128..255
  const int c0  = tid & 3;
  const int cs0 = c0 ^ ((r0 >> 1) & 3);
  const int cs1 = c0 ^ ((r1 >> 1) & 3);
  const int ld0 = tid * 8;            // ushort offset (16B per thread)
  const int ld1 = (512 + tid) * 8;

#define STAGE(ARR, srcp, kofs)                                                           \
  do {                                                                                   \
    __builtin_amdgcn_global_load_lds(                                                    \
      (const __attribute__((address_space(1))) void*)((srcp) + (size_t)r0*K + (kofs) + cs0*8), \
      (__attribute__((address_space(3))) void*)(&(ARR)[ld0]), 16, 0, 0);                 \
    __builtin_amdgcn_global_load_lds(                                                    \
      (const __attribute__((address_space(1))) void*)((srcp) + (size_t)r1*K + (kofs) + cs1*8), \
      (__attribute__((address_space(3))) void*)(&(ARR)[ld1]), 16, 0, 0);                 \
  } while(0)

  // fragment LDS offsets (ushort units); row-swizzle term identical for all
  // fragment rows of a wave (rows differ by multiples of 16 -> (row>>1)&3 fixed)
  const int swz  = fq ^ ((fr >> 1) & 3);
  const int offA = (wr*128 + fr) * 32 + swz * 8;
  const int offB = (wc*64  + fr) * 32 + swz * 8;

  f32x4 acc[8][4];
#pragma unroll
  for (int i = 0; i < 8; ++i)
#pragma unroll
    for (int j = 0; j < 4; ++j) acc[i][j] = {0.f,0.f,0.f,0.f};

  bf16x8 afr[8], bfr[4];

  // TILE: one K=32 step. 12 frag reads (parity P), optional stage of next
  // tile into P^1, 32 MFMA (counted lgkm by compiler), vm0, barrier.
#define TILE(P, STAGE_STMT)                                                \
  do {                                                                     \
    _Pragma("unroll")                                                      \
    for (int m2 = 0; m2 < 8; ++m2)                                         \
      afr[m2] = *(const bf16x8*)(&sA[P][offA + m2*512]);                   \
    _Pragma("unroll")                                                      \
    for (int n2 = 0; n2 < 4; ++n2)                                         \
      bfr[n2] = *(const bf16x8*)(&sB[P][offB + n2*512]);                   \
    STAGE_STMT;                                                            \
    __builtin_amdgcn_s_setprio(1);                                         \
    _Pragma("unroll")                                                      \
    for (int m2 = 0; m2 < 8; ++m2)                                         \
      _Pragma("unroll")                                                    \
      for (int n2 = 0; n2 < 4; ++n2)                                       \
        acc[m2][n2] = __builtin_amdgcn_mfma_f32_16x16x32_bf16(             \
            afr[m2], bfr[n2], acc[m2][n2], 0, 0, 0);                       \
    __builtin_amdgcn_s_setprio(0);                                         \
    WAIT_VM0();                                                            \
    BARRIER();                                                             \
    FENCE();                                                               \
  } while(0)

  const int nt = K >> 5;              // 32 K-tiles

  // prologue: stage tile 0 into parity 0
  STAGE(sA[0], Ag, 0);
  STAGE(sB[0], Bg, 0);
  WAIT_VM0();
  BARRIER();
  FENCE();

  // pair loop: tile 2i (par0, stages 2i+1), tile 2i+1 (par1, stages 2i+2)
  for (int i = 0; i < (nt >> 1) - 1; ++i){
    const int kbO = ((i << 1) + 1) << 5;
    const int kbE = ((i << 1) + 2) << 5;
    TILE(0, { STAGE(sA[1], Ag, kbO); STAGE(sB[1], Bg, kbO); });
    TILE(1, { STAGE(sA[0], Ag, kbE); STAGE(sB[0], Bg, kbE); });
  }
  TILE(0, { STAGE(sA[1], Ag, K - 32); STAGE(sB[1], Bg, K - 32); });
  TILE(1, );

  // ---------- epilogue (line-coalesced: ni innermost) ----------
  const int nb = bn*256 + wc*64;
  const int mb = bm*256 + wr*128;
  float bsv[4];
#pragma unroll
  for (int ni = 0; ni < 4; ++ni) bsv[ni] = bias[nb + ni*16 + fr];

  if (EPI == 0){
    const bool isV = (nb >= D_DIM);   // uniform per block (256-col tiles)
    unsigned short* dst = isV ? (outV + (nb - D_DIM)) : (outU + nb);
#pragma unroll
    for (int mi = 0; mi < 8; ++mi){
#pragma unroll
      for (int j = 0; j < 4; ++j){
        const int m = mb + mi*16 + fq*4 + j;
        unsigned short* row = dst + (size_t)m*D_DIM + fr;
#pragma unroll
        for (int ni = 0; ni < 4; ++ni){
          float cv = acc[mi][ni][j] + bsv[ni];
          row[ni*16] = f2bf(isV ? siluf_(cv) : cv);
        }
      }
    }
  } else {
    // h = acc + bias + resid stored as bf16 (halves GEMM2 write AND LN read)
#pragma unroll
    for (int mi = 0; mi < 8; ++mi){
#pragma unroll
      for (int j = 0; j < 4; ++j){
        const int m = mb + mi*16 + fq*4 + j;
        const float* rrow = resid + (size_t)m*D_DIM + nb + fr;
        unsigned short* orow = outU + (size_t)m*D_DIM + nb + fr;
#pragma unroll
        for (int ni = 0; ni < 4; ++ni)
          orow[ni*16] = f2bf(acc[mi][ni][j] + bsv[ni] + rrow[ni*16]);
      }
    }
  }
#undef TILE
#undef STAGE
#undef BARRIER
#undef FENCE
#undef WAIT_VM0
}

// ---------------- fused conv + chunked SSM scan ----------------
// Pass A: per-chunk local scan from h=0, write carry h_end[b][c][d]
__global__ __launch_bounds__(256) void scan_a(
    const unsigned short* __restrict__ v,
    const float* __restrict__ conv_w, const float* __restrict__ conv_b,
    const float* __restrict__ logit_a, const float* __restrict__ ssm_b,
    float* __restrict__ hend)
{
  const int b = blockIdx.x / NCHUNK;
  const int c = blockIdx.x % NCHUNK;
  const int d0 = threadIdx.x * 4;
  const int t0 = c * CLEN;
  const unsigned short* vb = v + (size_t)b * T_DIM * D_DIM;

  float w0[4], w1[4], w2[4], av[4], bv[4], cb[4];
#pragma unroll
  for (int i=0;i<4;i++){
    w0[i] = conv_w[(d0+i)*3+0];
    w1[i] = conv_w[(d0+i)*3+1];
    w2[i] = conv_w[(d0+i)*3+2];
    cb[i] = conv_b[d0+i];
    av[i] = sigmoidf_(logit_a[d0+i]);
    bv[i] = ssm_b[d0+i];
  }
  float vm1[4], v0[4], h[4] = {0.f,0.f,0.f,0.f};
  if (t0 == 0){
#pragma unroll
    for (int i=0;i<4;i++) vm1[i]=0.f;
  } else {
    ushort4 u = *(const ushort4*)(vb + (size_t)(t0-1)*D_DIM + d0);
    vm1[0]=bf2f(u.x); vm1[1]=bf2f(u.y); vm1[2]=bf2f(u.z); vm1[3]=bf2f(u.w);
  }
  {
    ushort4 u = *(const ushort4*)(vb + (size_t)t0*D_DIM + d0);
    v0[0]=bf2f(u.x); v0[1]=bf2f(u.y); v0[2]=bf2f(u.z); v0[3]=bf2f(u.w);
  }
#pragma unroll 8
  for (int t = t0; t < t0 + CLEN; ++t){
    float vp1[4];
    if (t + 1 < T_DIM){
      ushort4 u = *(const ushort4*)(vb + (size_t)(t+1)*D_DIM + d0);
      vp1[0]=bf2f(u.x); vp1[1]=bf2f(u.y); vp1[2]=bf2f(u.z); vp1[3]=bf2f(u.w);
    } else { vp1[0]=vp1[1]=vp1[2]=vp1[3]=0.f; }
#pragma unroll
    for (int i=0;i<4;i++){
      float vl = w0[i]*vm1[i] + w1[i]*v0[i] + w2[i]*vp1[i] + cb[i];
      h[i] = av[i]*h[i] + bv[i]*vl;
      vm1[i]=v0[i]; v0[i]=vp1[i];
    }
  }
  float* he = hend + ((size_t)b*NCHUNK + c)*D_DIM + d0;
#pragma unroll
  for (int i=0;i<4;i++) he[i] = h[i];
}

// combine carries across chunks: h_init[c] = aL*h_init[c-1] + h_end[c-1].
// batch-8 register prefetch breaks the 128-deep dependent-load chain.
__global__ void scan_fix(const float* __restrict__ hend, const float* __restrict__ logit_a,
                         float* __restrict__ hinit)
{
  int idx = blockIdx.x*blockDim.x + threadIdx.x;   // b*D + d
  if (idx >= B_DIM*D_DIM) return;
  const int b = idx / D_DIM, d = idx % D_DIM;
  const float a  = sigmoidf_(logit_a[d]);
  const float aL = __powf(a, (float)CLEN);
  const float* hep = hend  + (size_t)b*NCHUNK*D_DIM + d;
  float*       hip = hinit + (size_t)b*NCHUNK*D_DIM + d;
  float h = 0.f;
  for (int cb = 0; cb < NCHUNK; cb += 8){
    float buf[8];
#pragma unroll
    for (int j = 0; j < 8; ++j)
      buf[j] = hep[(size_t)(cb + j)*D_DIM];
#pragma unroll
    for (int j = 0; j < 8; ++j){
      hip[(size_t)(cb + j)*D_DIM] = h;
      h = aL*h + buf[j];
    }
  }
}

// Pass C: replay with correct h0; y = c*h + d*vl; gated = u * silu(y) -> bf16
__global__ __launch_bounds__(256) void scan_c(
    const unsigned short* __restrict__ v,
    const unsigned short* __restrict__ ubuf,
    const float* __restrict__ conv_w, const float* __restrict__ conv_b,
    const float* __restrict__ logit_a, const float* __restrict__ ssm_b,
    const float* __restrict__ ssm_c, const float* __restrict__ ssm_d,
    const float* __restrict__ hinit,
    unsigned short* __restrict__ gated)
{
  const int b = blockIdx.x / NCHUNK;
  const int c = blockIdx.x % NCHUNK;
  const int d0 = threadIdx.x * 4;
  const int t0 = c * CLEN;
  const unsigned short* vb = v    + (size_t)b * T_DIM * D_DIM;
  const unsigned short* ub = ubuf + (size_t)b * T_DIM * D_DIM;
  unsigned short* gb       = gated+ (size_t)b * T_DIM * D_DIM;

  float w0[4], w1[4], w2[4], av[4], bv[4], cb[4], scv[4], sdv[4], h[4];
#pragma unroll
  for (int i=0;i<4;i++){
    w0[i] = conv_w[(d0+i)*3+0];
    w1[i] = conv_w[(d0+i)*3+1];
    w2[i] = conv_w[(d0+i)*3+2];
    cb[i] = conv_b[d0+i];
    av[i] = sigmoidf_(logit_a[d0+i]);
    bv[i] = ssm_b[d0+i];
    scv[i] = ssm_c[d0+i];
    sdv[i] = ssm_d[d0+i];
    h[i] = hinit[((size_t)b*NCHUNK + c)*D_DIM + d0 + i];
  }
  float vm1[4], v0[4];
  if (t0 == 0){
#pragma unroll
    for (int i=0;i<4;i++) vm1[i]=0.f;
  } else {
    ushort4 u = *(const ushort4*)(vb + (size_t)(t0-1)*D_DIM + d0);
    vm1[0]=bf2f(u.x); vm1[1]=bf2f(u.y); vm1[2]=bf2f(u.z); vm1[3]=bf2f(u.w);
  }
  {
    ushort4 u = *(const ushort4*)(vb + (size_t)t0*D_DIM + d0);
    v0[0]=bf2f(u.x); v0[1]=bf2f(u.y); v0[2]=bf2f(u.z); v0[3]=bf2f(u.w);
  }
#pragma unroll 8
  for (int t = t0; t < t0 + CLEN; ++t){
    float vp1[4];
    if (t + 1 < T_DIM){
      ushort4 u = *(const ushort4*)(vb + (size_t)(t+1)*D_DIM + d0);
      vp1[0]=bf2f(u.x); vp1[1]=bf2f(u.y); vp1[2]=bf2f(u.z); vp1[3]=bf2f(u.w);
    } else { vp1[0]=vp1[1]=vp1[2]=vp1[3]=0.f; }
    ushort4 uu = *(const ushort4*)(ub + (size_t)t*D_DIM + d0);
    float uf[4] = { bf2f(uu.x), bf2f(uu.y), bf2f(uu.z), bf2f(uu.w) };
    ushort4 go;
    unsigned short gtmp[4];
#pragma unroll
    for (int i=0;i<4;i++){
      float vl = w0[i]*vm1[i] + w1[i]*v0[i] + w2[i]*vp1[i] + cb[i];
      h[i] = av[i]*h[i] + bv[i]*vl;
      float y = scv[i]*h[i] + sdv[i]*vl;
      gtmp[i] = f2bf(uf[i] * siluf_(y));
      vm1[i]=v0[i]; v0[i]=vp1[i];
    }
    go.x=gtmp[0]; go.y=gtmp[1]; go.z=gtmp[2]; go.w=gtmp[3];
    *(ushort4*)(gb + (size_t)t*D_DIM + d0) = go;
  }
}

// ---------------- LayerNorm (bf16 h in, fp32 out; one block per row) ----------------
__global__ __launch_bounds__(256) void ln_kernel(
    const unsigned short* __restrict__ hb, float* __restrict__ out,
    const float* __restrict__ lw, const float* __restrict__ lb)
{
  __shared__ float rs[4], rq[4];
  const int row = blockIdx.x;
  const int tid = threadIdx.x;
  const unsigned short* p = hb + (size_t)row * D_DIM;
  ushort4 u = *(const ushort4*)(p + tid*4);
  float x0 = bf2f(u.x), x1 = bf2f(u.y), x2 = bf2f(u.z), x3 = bf2f(u.w);
  float s = x0 + x1 + x2 + x3;
  float q = x0*x0 + x1*x1 + x2*x2 + x3*x3;
#pragma unroll
  for (int off = 32; off > 0; off >>= 1){
    s += __shfl_down(s, off, 64);
    q += __shfl_down(q, off, 64);
  }
  const int wv = tid >> 6;
  if ((tid & 63) == 0){ rs[wv] = s; rq[wv] = q; }
  __syncthreads();
  const float ts = rs[0]+rs[1]+rs[2]+rs[3];
  const float tq = rq[0]+rq[1]+rq[2]+rq[3];
  const float mu  = ts * (1.f/(float)D_DIM);
  const float var = tq * (1.f/(float)D_DIM) - mu*mu;
  const float inv = rsqrtf(var + LN_EPS);
  const float4 w4 = *(const float4*)(lw + tid*4);
  const float4 b4 = *(const float4*)(lb + tid*4);
  float4 o;
  o.x = (x0-mu)*inv*w4.x + b4.x;
  o.y = (x1-mu)*inv*w4.y + b4.y;
  o.z = (x2-mu)*inv*w4.z + b4.z;
  o.w = (x3-mu)*inv*w4.w + b4.w;
  *(float4*)(out + (size_t)row*D_DIM + tid*4) = o;
}

// ---------------- launch ----------------
extern "C" void kernel_launch(void* const* d_in, const int* in_sizes, int n_in,
                              void* d_out, int out_size, void* d_ws, size_t ws_size,
                              hipStream_t stream)
{
  const float* x     = (const float*)d_in[0];
  const float* w1    = (const float*)d_in[1];
  const float* b1    = (const float*)d_in[2];
  const float* convw = (const float*)d_in[3];
  const float* convb = (const float*)d_in[4];
  const float* la    = (const float*)d_in[5];
  const float* sb    = (const float*)d_in[6];
  const float* sc    = (const float*)d_in[7];
  const float* sd    = (const float*)d_in[8];
  const float* w2    = (const float*)d_in[9];
  const float* b2    = (const float*)d_in[10];
  const float* lw    = (const float*)d_in[11];
  const float* lb    = (const float*)d_in[12];
  float* out = (float*)d_out;

  char* ws = (char*)d_ws;
  unsigned short* xb    = (unsigned short*)(ws + 0);          // x bf16; reused as gated
  unsigned short* ubf   = (unsigned short*)(ws + 67108864);   // u; reused as h (bf16) after scan_c
  unsigned short* vbf   = (unsigned short*)(ws + 134217728);  // v (silu'd)
  unsigned short* w1t   = (unsigned short*)(ws + 201326592);
  unsigned short* w2t   = (unsigned short*)(ws + 205520896);
  float*          hend  = (float*)(ws + 207618048);
  float*          hinit = (float*)(ws + 211812352);

  cvt_f32_bf16<<<2048, 256, 0, stream>>>(x, xb, BT_DIM*D_DIM);
  cvt_transpose<<<(D_DIM/32)*(TWO_D/32), 256, 0, stream>>>(w1, w1t, D_DIM, TWO_D);
  cvt_transpose<<<(D_DIM/32)*(D_DIM/32), 256, 0, stream>>>(w2, w2t, D_DIM, D_DIM);

  // GEMM1: M=32768, N=2048, K=1024 -> 1024 blocks
  gemm256<0><<<dim3((BT_DIM/256)*(TWO_D/256)), 512, 0, stream>>>(
      xb, w1t, b1, nullptr, ubf, vbf, D_DIM, TWO_D/256);

  scan_a<<<B_DIM*NCHUNK, 256, 0, stream>>>(vbf, convw, convb, la, sb, hend);
  scan_fix<<<(B_DIM*D_DIM + 255)/256, 256, 0, stream>>>(hend, la, hinit);
  scan_c<<<B_DIM*NCHUNK, 256, 0, stream>>>(vbf, ubf, convw, convb, la, sb, sc, sd, hinit, xb);

  // GEMM2: M=32768, N=1024, K=1024 -> 512 blocks; h (bf16) -> ubf
  gemm256<1><<<dim3((BT_DIM/256)*(D_DIM/256)), 512, 0, stream>>>(
      xb, w2t, b2, x, ubf, nullptr, D_DIM, D_DIM/256);

  ln_kernel<<<BT_DIM, 256, 0, stream>>>(ubf, out, lw, lb);
}

// Round 15
// 418.922 us; speedup vs baseline: 6.4927x; 6.4927x over previous
//
#include <hip/hip_runtime.h>
#include <cstdint>
#include <cstddef>

#define D_DIM   1024
#define TWO_D   2048
#define B_DIM   8
#define T_DIM   4096
#define BT_DIM  (B_DIM*T_DIM)     // 32768 rows
#define LN_EPS  1e-5f
#define NCHUNK  128
#define CLEN    (T_DIM/NCHUNK)    // 32 steps per chunk

typedef __attribute__((ext_vector_type(8))) short bf16x8;
typedef __attribute__((ext_vector_type(4))) float f32x4;

__device__ __forceinline__ float bf2f(unsigned short u){
  union { unsigned int i; float f; } c; c.i = ((unsigned int)u) << 16; return c.f;
}
__device__ __forceinline__ unsigned short f2bf(float f){
  union { float f; unsigned int i; } c; c.f = f;
  unsigned int x = c.i;
  return (unsigned short)((x + 0x7fffu + ((x >> 16) & 1u)) >> 16);
}
__device__ __forceinline__ float sigmoidf_(float x){ return 1.f/(1.f+__expf(-x)); }
__device__ __forceinline__ float siluf_(float x){ return x/(1.f+__expf(-x)); }

// ---------------- conversion kernels ----------------

__global__ void cvt_f32_bf16(const float* __restrict__ in, unsigned short* __restrict__ out, int n){
  int i = (blockIdx.x*blockDim.x + threadIdx.x)*4;
  const int stride = gridDim.x*blockDim.x*4;
  for (; i + 3 < n; i += stride){
    float4 f = *(const float4*)(in + i);
    ushort4 o; o.x=f2bf(f.x); o.y=f2bf(f.y); o.z=f2bf(f.z); o.w=f2bf(f.w);
    *(ushort4*)(out + i) = o;
  }
}

// LDS-tiled transpose: W (rows x cols, fp32) -> Wt (cols x rows, bf16).
__global__ __launch_bounds__(256) void cvt_transpose(
    const float* __restrict__ W, unsigned short* __restrict__ Wt,
    int rows, int cols)
{
  __shared__ float tile[32][33];
  const int tx = threadIdx.x & 31;
  const int ty = threadIdx.x >> 5;        // 0..7
  const int tpc = cols >> 5;
  const int bc = blockIdx.x % tpc;
  const int br = blockIdx.x / tpc;
  const int gc = bc*32 + tx;
  const int gr = br*32;
#pragma unroll
  for (int i = 0; i < 32; i += 8)
    tile[ty + i][tx] = W[(size_t)(gr + ty + i)*cols + gc];
  __syncthreads();
#pragma unroll
  for (int i = 0; i < 32; i += 8)
    Wt[(size_t)(bc*32 + ty + i)*rows + gr + tx] = f2bf(tile[tx][ty + i]);
}

// ---------------- 256x256 GEMM, BK=32, 1 phase/tile, 2 blocks/CU (R15) ----------------
// R14's occupancy experiment with the VGPR-cap bug fixed: launch_bounds(512,2)
// (min 2 waves/EU -> VGPR cap 256; natural alloc 128 for this layout, R10) so
// occupancy = min(LDS 64KB -> 2 blocks, VGPR 128 -> 2 blocks) = 2 blocks/CU.
// One phase per K-tile: {12 frag ds_reads (parity P), stage next tile into
// P^1 (4 glds), 32 MFMA (compiler-counted lgkm waits), vm0, barrier}.
// Cross-block overlap (m114) should fill this block's drain windows.
template<int EPI>
__global__ __launch_bounds__(512, 2) void gemm256(
    const unsigned short* __restrict__ A,    // M x K bf16
    const unsigned short* __restrict__ Bt,   // N x K bf16
    const float* __restrict__ bias,          // N
    const float* __restrict__ resid,         // M x 1024 fp32 (EPI 1)
    unsigned short* __restrict__ outU,
    unsigned short* __restrict__ outV,
    const int K, const int nbn)
{
  __shared__ __align__(16) unsigned short sA[2][8192];   // [parity][256 rows x 32 cols]
  __shared__ __align__(16) unsigned short sB[2][8192];

#define BARRIER()   __builtin_amdgcn_s_barrier()
#define FENCE()     __builtin_amdgcn_sched_barrier(0)
#define WAIT_VM0()  do { asm volatile("s_waitcnt vmcnt(0)"); } while(0)

  const int tid  = threadIdx.x;
  const int lane = tid & 63;
  const int wv   = tid >> 6;          // 0..7
  const int wr   = wv >> 2;           // 0..1  (M half)
  const int wc   = wv & 3;            // 0..3  (N quarter)
  const int fr   = lane & 15;
  const int fq   = lane >> 4;

  // bijective XCD swizzle (nwg % 8 == 0 by construction)
  const int nwg = gridDim.x;
  const int cpx = nwg >> 3;
  const int wg  = (blockIdx.x & 7) * cpx + (blockIdx.x >> 3);
  const int bm = wg / nbn, bn = wg % nbn;

  const unsigned short* Ag = A  + (size_t)bm * 256 * K;
  const unsigned short* Bg = Bt + (size_t)bn * 256 * K;

  // staging: thread -> (row = tid>>2 [+128], 16B chunk = tid&3), LDS linear,
  // global column chunk XOR-swizzled (involution, same XOR applied on read)
  const int r0  = tid >> 2;           // rows 0..127
  const int r1  = 128 + r0;           // rows 128..255
  const int c0  = tid & 3;
  const int cs0 = c0 ^ ((r0 >> 1) & 3);
  const int cs1 = c0 ^ ((r1 >> 1) & 3);
  const int ld0 = tid * 8;            // ushort offset (16B per thread)
  const int ld1 = (512 + tid) * 8;

#define STAGE(ARR, srcp, kofs)                                                           \
  do {                                                                                   \
    __builtin_amdgcn_global_load_lds(                                                    \
      (const __attribute__((address_space(1))) void*)((srcp) + (size_t)r0*K + (kofs) + cs0*8), \
      (__attribute__((address_space(3))) void*)(&(ARR)[ld0]), 16, 0, 0);                 \
    __builtin_amdgcn_global_load_lds(                                                    \
      (const __attribute__((address_space(1))) void*)((srcp) + (size_t)r1*K + (kofs) + cs1*8), \
      (__attribute__((address_space(3))) void*)(&(ARR)[ld1]), 16, 0, 0);                 \
  } while(0)

  // fragment LDS offsets (ushort units); row-swizzle term identical for all
  // fragment rows of a wave (rows differ by multiples of 16 -> (row>>1)&3 fixed)
  const int swz  = fq ^ ((fr >> 1) & 3);
  const int offA = (wr*128 + fr) * 32 + swz * 8;
  const int offB = (wc*64  + fr) * 32 + swz * 8;

  f32x4 acc[8][4];
#pragma unroll
  for (int i = 0; i < 8; ++i)
#pragma unroll
    for (int j = 0; j < 4; ++j) acc[i][j] = {0.f,0.f,0.f,0.f};

  bf16x8 afr[8], bfr[4];

  // TILE: one K=32 step. 12 frag reads (parity P), optional stage of next
  // tile into P^1, 32 MFMA (counted lgkm by compiler), vm0, barrier.
#define TILE(P, STAGE_STMT)                                                \
  do {                                                                     \
    _Pragma("unroll")                                                      \
    for (int m2 = 0; m2 < 8; ++m2)                                         \
      afr[m2] = *(const bf16x8*)(&sA[P][offA + m2*512]);                   \
    _Pragma("unroll")                                                      \
    for (int n2 = 0; n2 < 4; ++n2)                                         \
      bfr[n2] = *(const bf16x8*)(&sB[P][offB + n2*512]);                   \
    STAGE_STMT;                                                            \
    __builtin_amdgcn_s_setprio(1);                                         \
    _Pragma("unroll")                                                      \
    for (int m2 = 0; m2 < 8; ++m2)                                         \
      _Pragma("unroll")                                                    \
      for (int n2 = 0; n2 < 4; ++n2)                                       \
        acc[m2][n2] = __builtin_amdgcn_mfma_f32_16x16x32_bf16(             \
            afr[m2], bfr[n2], acc[m2][n2], 0, 0, 0);                       \
    __builtin_amdgcn_s_setprio(0);                                         \
    WAIT_VM0();                                                            \
    BARRIER();                                                             \
    FENCE();                                                               \
  } while(0)

  const int nt = K >> 5;              // 32 K-tiles

  // prologue: stage tile 0 into parity 0
  STAGE(sA[0], Ag, 0);
  STAGE(sB[0], Bg, 0);
  WAIT_VM0();
  BARRIER();
  FENCE();

  // pair loop: tile 2i (par0, stages 2i+1), tile 2i+1 (par1, stages 2i+2)
  for (int i = 0; i < (nt >> 1) - 1; ++i){
    const int kbO = ((i << 1) + 1) << 5;
    const int kbE = ((i << 1) + 2) << 5;
    TILE(0, { STAGE(sA[1], Ag, kbO); STAGE(sB[1], Bg, kbO); });
    TILE(1, { STAGE(sA[0], Ag, kbE); STAGE(sB[0], Bg, kbE); });
  }
  TILE(0, { STAGE(sA[1], Ag, K - 32); STAGE(sB[1], Bg, K - 32); });
  TILE(1, );

  // ---------- epilogue (line-coalesced: ni innermost) ----------
  const int nb = bn*256 + wc*64;
  const int mb = bm*256 + wr*128;
  float bsv[4];
#pragma unroll
  for (int ni = 0; ni < 4; ++ni) bsv[ni] = bias[nb + ni*16 + fr];

  if (EPI == 0){
    const bool isV = (nb >= D_DIM);   // uniform per block (256-col tiles)
    unsigned short* dst = isV ? (outV + (nb - D_DIM)) : (outU + nb);
#pragma unroll
    for (int mi = 0; mi < 8; ++mi){
#pragma unroll
      for (int j = 0; j < 4; ++j){
        const int m = mb + mi*16 + fq*4 + j;
        unsigned short* row = dst + (size_t)m*D_DIM + fr;
#pragma unroll
        for (int ni = 0; ni < 4; ++ni){
          float cv = acc[mi][ni][j] + bsv[ni];
          row[ni*16] = f2bf(isV ? siluf_(cv) : cv);
        }
      }
    }
  } else {
    // h = acc + bias + resid stored as bf16 (halves GEMM2 write AND LN read)
#pragma unroll
    for (int mi = 0; mi < 8; ++mi){
#pragma unroll
      for (int j = 0; j < 4; ++j){
        const int m = mb + mi*16 + fq*4 + j;
        const float* rrow = resid + (size_t)m*D_DIM + nb + fr;
        unsigned short* orow = outU + (size_t)m*D_DIM + nb + fr;
#pragma unroll
        for (int ni = 0; ni < 4; ++ni)
          orow[ni*16] = f2bf(acc[mi][ni][j] + bsv[ni] + rrow[ni*16]);
      }
    }
  }
#undef TILE
#undef STAGE
#undef BARRIER
#undef FENCE
#undef WAIT_VM0
}

// ---------------- fused conv + chunked SSM scan ----------------
// Pass A: per-chunk local scan from h=0, write carry h_end[b][c][d]
__global__ __launch_bounds__(256) void scan_a(
    const unsigned short* __restrict__ v,
    const float* __restrict__ conv_w, const float* __restrict__ conv_b,
    const float* __restrict__ logit_a, const float* __restrict__ ssm_b,
    float* __restrict__ hend)
{
  const int b = blockIdx.x / NCHUNK;
  const int c = blockIdx.x % NCHUNK;
  const int d0 = threadIdx.x * 4;
  const int t0 = c * CLEN;
  const unsigned short* vb = v + (size_t)b * T_DIM * D_DIM;

  float w0[4], w1[4], w2[4], av[4], bv[4], cb[4];
#pragma unroll
  for (int i=0;i<4;i++){
    w0[i] = conv_w[(d0+i)*3+0];
    w1[i] = conv_w[(d0+i)*3+1];
    w2[i] = conv_w[(d0+i)*3+2];
    cb[i] = conv_b[d0+i];
    av[i] = sigmoidf_(logit_a[d0+i]);
    bv[i] = ssm_b[d0+i];
  }
  float vm1[4], v0[4], h[4] = {0.f,0.f,0.f,0.f};
  if (t0 == 0){
#pragma unroll
    for (int i=0;i<4;i++) vm1[i]=0.f;
  } else {
    ushort4 u = *(const ushort4*)(vb + (size_t)(t0-1)*D_DIM + d0);
    vm1[0]=bf2f(u.x); vm1[1]=bf2f(u.y); vm1[2]=bf2f(u.z); vm1[3]=bf2f(u.w);
  }
  {
    ushort4 u = *(const ushort4*)(vb + (size_t)t0*D_DIM + d0);
    v0[0]=bf2f(u.x); v0[1]=bf2f(u.y); v0[2]=bf2f(u.z); v0[3]=bf2f(u.w);
  }
#pragma unroll 8
  for (int t = t0; t < t0 + CLEN; ++t){
    float vp1[4];
    if (t + 1 < T_DIM){
      ushort4 u = *(const ushort4*)(vb + (size_t)(t+1)*D_DIM + d0);
      vp1[0]=bf2f(u.x); vp1[1]=bf2f(u.y); vp1[2]=bf2f(u.z); vp1[3]=bf2f(u.w);
    } else { vp1[0]=vp1[1]=vp1[2]=vp1[3]=0.f; }
#pragma unroll
    for (int i=0;i<4;i++){
      float vl = w0[i]*vm1[i] + w1[i]*v0[i] + w2[i]*vp1[i] + cb[i];
      h[i] = av[i]*h[i] + bv[i]*vl;
      vm1[i]=v0[i]; v0[i]=vp1[i];
    }
  }
  float* he = hend + ((size_t)b*NCHUNK + c)*D_DIM + d0;
#pragma unroll
  for (int i=0;i<4;i++) he[i] = h[i];
}

// combine carries across chunks: h_init[c] = aL*h_init[c-1] + h_end[c-1].
// batch-8 register prefetch breaks the 128-deep dependent-load chain.
__global__ void scan_fix(const float* __restrict__ hend, const float* __restrict__ logit_a,
                         float* __restrict__ hinit)
{
  int idx = blockIdx.x*blockDim.x + threadIdx.x;   // b*D + d
  if (idx >= B_DIM*D_DIM) return;
  const int b = idx / D_DIM, d = idx % D_DIM;
  const float a  = sigmoidf_(logit_a[d]);
  const float aL = __powf(a, (float)CLEN);
  const float* hep = hend  + (size_t)b*NCHUNK*D_DIM + d;
  float*       hip = hinit + (size_t)b*NCHUNK*D_DIM + d;
  float h = 0.f;
  for (int cb = 0; cb < NCHUNK; cb += 8){
    float buf[8];
#pragma unroll
    for (int j = 0; j < 8; ++j)
      buf[j] = hep[(size_t)(cb + j)*D_DIM];
#pragma unroll
    for (int j = 0; j < 8; ++j){
      hip[(size_t)(cb + j)*D_DIM] = h;
      h = aL*h + buf[j];
    }
  }
}

// Pass C: replay with correct h0; y = c*h + d*vl; gated = u * silu(y) -> bf16
__global__ __launch_bounds__(256) void scan_c(
    const unsigned short* __restrict__ v,
    const unsigned short* __restrict__ ubuf,
    const float* __restrict__ conv_w, const float* __restrict__ conv_b,
    const float* __restrict__ logit_a, const float* __restrict__ ssm_b,
    const float* __restrict__ ssm_c, const float* __restrict__ ssm_d,
    const float* __restrict__ hinit,
    unsigned short* __restrict__ gated)
{
  const int b = blockIdx.x / NCHUNK;
  const int c = blockIdx.x % NCHUNK;
  const int d0 = threadIdx.x * 4;
  const int t0 = c * CLEN;
  const unsigned short* vb = v    + (size_t)b * T_DIM * D_DIM;
  const unsigned short* ub = ubuf + (size_t)b * T_DIM * D_DIM;
  unsigned short* gb       = gated+ (size_t)b * T_DIM * D_DIM;

  float w0[4], w1[4], w2[4], av[4], bv[4], cb[4], scv[4], sdv[4], h[4];
#pragma unroll
  for (int i=0;i<4;i++){
    w0[i] = conv_w[(d0+i)*3+0];
    w1[i] = conv_w[(d0+i)*3+1];
    w2[i] = conv_w[(d0+i)*3+2];
    cb[i] = conv_b[d0+i];
    av[i] = sigmoidf_(logit_a[d0+i]);
    bv[i] = ssm_b[d0+i];
    scv[i] = ssm_c[d0+i];
    sdv[i] = ssm_d[d0+i];
    h[i] = hinit[((size_t)b*NCHUNK + c)*D_DIM + d0 + i];
  }
  float vm1[4], v0[4];
  if (t0 == 0){
#pragma unroll
    for (int i=0;i<4;i++) vm1[i]=0.f;
  } else {
    ushort4 u = *(const ushort4*)(vb + (size_t)(t0-1)*D_DIM + d0);
    vm1[0]=bf2f(u.x); vm1[1]=bf2f(u.y); vm1[2]=bf2f(u.z); vm1[3]=bf2f(u.w);
  }
  {
    ushort4 u = *(const ushort4*)(vb + (size_t)t0*D_DIM + d0);
    v0[0]=bf2f(u.x); v0[1]=bf2f(u.y); v0[2]=bf2f(u.z); v0[3]=bf2f(u.w);
  }
#pragma unroll 8
  for (int t = t0; t < t0 + CLEN; ++t){
    float vp1[4];
    if (t + 1 < T_DIM){
      ushort4 u = *(const ushort4*)(vb + (size_t)(t+1)*D_DIM + d0);
      vp1[0]=bf2f(u.x); vp1[1]=bf2f(u.y); vp1[2]=bf2f(u.z); vp1[3]=bf2f(u.w);
    } else { vp1[0]=vp1[1]=vp1[2]=vp1[3]=0.f; }
    ushort4 uu = *(const ushort4*)(ub + (size_t)t*D_DIM + d0);
    float uf[4] = { bf2f(uu.x), bf2f(uu.y), bf2f(uu.z), bf2f(uu.w) };
    ushort4 go;
    unsigned short gtmp[4];
#pragma unroll
    for (int i=0;i<4;i++){
      float vl = w0[i]*vm1[i] + w1[i]*v0[i] + w2[i]*vp1[i] + cb[i];
      h[i] = av[i]*h[i] + bv[i]*vl;
      float y = scv[i]*h[i] + sdv[i]*vl;
      gtmp[i] = f2bf(uf[i] * siluf_(y));
      vm1[i]=v0[i]; v0[i]=vp1[i];
    }
    go.x=gtmp[0]; go.y=gtmp[1]; go.z=gtmp[2]; go.w=gtmp[3];
    *(ushort4*)(gb + (size_t)t*D_DIM + d0) = go;
  }
}

// ---------------- LayerNorm (bf16 h in, fp32 out; one block per row) ----------------
__global__ __launch_bounds__(256) void ln_kernel(
    const unsigned short* __restrict__ hb, float* __restrict__ out,
    const float* __restrict__ lw, const float* __restrict__ lb)
{
  __shared__ float rs[4], rq[4];
  const int row = blockIdx.x;
  const int tid = threadIdx.x;
  const unsigned short* p = hb + (size_t)row * D_DIM;
  ushort4 u = *(const ushort4*)(p + tid*4);
  float x0 = bf2f(u.x), x1 = bf2f(u.y), x2 = bf2f(u.z), x3 = bf2f(u.w);
  float s = x0 + x1 + x2 + x3;
  float q = x0*x0 + x1*x1 + x2*x2 + x3*x3;
#pragma unroll
  for (int off = 32; off > 0; off >>= 1){
    s += __shfl_down(s, off, 64);
    q += __shfl_down(q, off, 64);
  }
  const int wv = tid >> 6;
  if ((tid & 63) == 0){ rs[wv] = s; rq[wv] = q; }
  __syncthreads();
  const float ts = rs[0]+rs[1]+rs[2]+rs[3];
  const float tq = rq[0]+rq[1]+rq[2]+rq[3];
  const float mu  = ts * (1.f/(float)D_DIM);
  const float var = tq * (1.f/(float)D_DIM) - mu*mu;
  const float inv = rsqrtf(var + LN_EPS);
  const float4 w4 = *(const float4*)(lw + tid*4);
  const float4 b4 = *(const float4*)(lb + tid*4);
  float4 o;
  o.x = (x0-mu)*inv*w4.x + b4.x;
  o.y = (x1-mu)*inv*w4.y + b4.y;
  o.z = (x2-mu)*inv*w4.z + b4.z;
  o.w = (x3-mu)*inv*w4.w + b4.w;
  *(float4*)(out + (size_t)row*D_DIM + tid*4) = o;
}

// ---------------- launch ----------------
extern "C" void kernel_launch(void* const* d_in, const int* in_sizes, int n_in,
                              void* d_out, int out_size, void* d_ws, size_t ws_size,
                              hipStream_t stream)
{
  const float* x     = (const float*)d_in[0];
  const float* w1    = (const float*)d_in[1];
  const float* b1    = (const float*)d_in[2];
  const float* convw = (const float*)d_in[3];
  const float* convb = (const float*)d_in[4];
  const float* la    = (const float*)d_in[5];
  const float* sb    = (const float*)d_in[6];
  const float* sc    = (const float*)d_in[7];
  const float* sd    = (const float*)d_in[8];
  const float* w2    = (const float*)d_in[9];
  const float* b2    = (const float*)d_in[10];
  const float* lw    = (const float*)d_in[11];
  const float* lb    = (const float*)d_in[12];
  float* out = (float*)d_out;

  char* ws = (char*)d_ws;
  unsigned short* xb    = (unsigned short*)(ws + 0);          // x bf16; reused as gated
  unsigned short* ubf   = (unsigned short*)(ws + 67108864);   // u; reused as h (bf16) after scan_c
  unsigned short* vbf   = (unsigned short*)(ws + 134217728);  // v (silu'd)
  unsigned short* w1t   = (unsigned short*)(ws + 201326592);
  unsigned short* w2t   = (unsigned short*)(ws + 205520896);
  float*          hend  = (float*)(ws + 207618048);
  float*          hinit = (float*)(ws + 211812352);

  cvt_f32_bf16<<<2048, 256, 0, stream>>>(x, xb, BT_DIM*D_DIM);
  cvt_transpose<<<(D_DIM/32)*(TWO_D/32), 256, 0, stream>>>(w1, w1t, D_DIM, TWO_D);
  cvt_transpose<<<(D_DIM/32)*(D_DIM/32), 256, 0, stream>>>(w2, w2t, D_DIM, D_DIM);

  // GEMM1: M=32768, N=2048, K=1024 -> 1024 blocks
  gemm256<0><<<dim3((BT_DIM/256)*(TWO_D/256)), 512, 0, stream>>>(
      xb, w1t, b1, nullptr, ubf, vbf, D_DIM, TWO_D/256);

  scan_a<<<B_DIM*NCHUNK, 256, 0, stream>>>(vbf, convw, convb, la, sb, hend);
  scan_fix<<<(B_DIM*D_DIM + 255)/256, 256, 0, stream>>>(hend, la, hinit);
  scan_c<<<B_DIM*NCHUNK, 256, 0, stream>>>(vbf, ubf, convw, convb, la, sb, sc, sd, hinit, xb);

  // GEMM2: M=32768, N=1024, K=1024 -> 512 blocks; h (bf16) -> ubf
  gemm256<1><<<dim3((BT_DIM/256)*(D_DIM/256)), 512, 0, stream>>>(
      xb, w2t, b2, x, ubf, nullptr, D_DIM, D_DIM/256);

  ln_kernel<<<BT_DIM, 256, 0, stream>>>(ubf, out, lw, lb);
}

// Round 16
// 393.483 us; speedup vs baseline: 6.9124x; 1.0647x over previous
//
#include <hip/hip_runtime.h>
#include <cstdint>
#include <cstddef>

#define D_DIM   1024
#define TWO_D   2048
#define B_DIM   8
#define T_DIM   4096
#define BT_DIM  (B_DIM*T_DIM)     // 32768 rows
#define LN_EPS  1e-5f
#define NCHUNK  128
#define CLEN    (T_DIM/NCHUNK)    // 32 steps per chunk

typedef __attribute__((ext_vector_type(8))) short bf16x8;
typedef __attribute__((ext_vector_type(4))) float f32x4;

__device__ __forceinline__ float bf2f(unsigned short u){
  union { unsigned int i; float f; } c; c.i = ((unsigned int)u) << 16; return c.f;
}
__device__ __forceinline__ unsigned short f2bf(float f){
  union { float f; unsigned int i; } c; c.f = f;
  unsigned int x = c.i;
  return (unsigned short)((x + 0x7fffu + ((x >> 16) & 1u)) >> 16);
}
__device__ __forceinline__ float sigmoidf_(float x){ return 1.f/(1.f+__expf(-x)); }
__device__ __forceinline__ float siluf_(float x){ return x/(1.f+__expf(-x)); }

// ---------------- conversion kernels ----------------

__global__ void cvt_f32_bf16(const float* __restrict__ in, unsigned short* __restrict__ out, int n){
  int i = (blockIdx.x*blockDim.x + threadIdx.x)*4;
  const int stride = gridDim.x*blockDim.x*4;
  for (; i + 3 < n; i += stride){
    float4 f = *(const float4*)(in + i);
    ushort4 o; o.x=f2bf(f.x); o.y=f2bf(f.y); o.z=f2bf(f.z); o.w=f2bf(f.w);
    *(ushort4*)(out + i) = o;
  }
}

// LDS-tiled transpose: W (rows x cols, fp32) -> Wt (cols x rows, bf16).
__global__ __launch_bounds__(256) void cvt_transpose(
    const float* __restrict__ W, unsigned short* __restrict__ Wt,
    int rows, int cols)
{
  __shared__ float tile[32][33];
  const int tx = threadIdx.x & 31;
  const int ty = threadIdx.x >> 5;        // 0..7
  const int tpc = cols >> 5;
  const int bc = blockIdx.x % tpc;
  const int br = blockIdx.x / tpc;
  const int gc = bc*32 + tx;
  const int gr = br*32;
#pragma unroll
  for (int i = 0; i < 32; i += 8)
    tile[ty + i][tx] = W[(size_t)(gr + ty + i)*cols + gc];
  __syncthreads();
#pragma unroll
  for (int i = 0; i < 32; i += 8)
    Wt[(size_t)(bc*32 + ty + i)*rows + gr + tx] = f2bf(tile[tx][ty + i]);
}

// ---------------- 256x256 8-phase GEMM (session-final structure) ----------------
// Literal parity (compiler proves frag reads don't alias in-flight LDS-DMAs ->
// no hidden vmcnt drains), counted vmcnt(4) twice/tile before end barriers
// (cross-wave DMA-landing guarantee), no manual lgkm drain (compiler inserts
// counted lgkm waits), setprio around MFMA cluster, XOR read/source swizzle
// (0 bank conflicts), bijective XCD swizzle. Measured: 755 TF, MfmaUtil 33%.
// Falsified-null variants (kept for the record): frag double-buffer (R8),
// MFMA loop order (R9), 2-phase/tile (R10), 128^2 tile 4 blk/CU (R11),
// no-lgkm-drain delta (R12), BK=32 + 2 blk/CU (R14/R15).
// EPI 0: uv = A@B + bias; n<1024 -> u (bf16), n>=1024 -> silu -> v (bf16)
// EPI 1: h = A@B + bias + resid -> outU (bf16, halves GEMM2 write + LN read)
template<int EPI>
__global__ __launch_bounds__(512, 2) void gemm256(
    const unsigned short* __restrict__ A,    // M x K bf16
    const unsigned short* __restrict__ Bt,   // N x K bf16
    const float* __restrict__ bias,          // N
    const float* __restrict__ resid,         // M x 1024 fp32 (EPI 1)
    unsigned short* __restrict__ outU,
    unsigned short* __restrict__ outV,
    const int K, const int nbn)
{
  __shared__ __align__(16) unsigned short sA[2][2][8192];
  __shared__ __align__(16) unsigned short sB[2][2][8192];

#define BARRIER()   __builtin_amdgcn_s_barrier()
#define FENCE()     __builtin_amdgcn_sched_barrier(0)
#define WAIT_VM4()  do { asm volatile("s_waitcnt vmcnt(4)"); FENCE(); } while(0)
#define WAIT_VM0()  do { asm volatile("s_waitcnt vmcnt(0)"); FENCE(); } while(0)

  const int tid  = threadIdx.x;
  const int lane = tid & 63;
  const int wv   = tid >> 6;          // 0..7
  const int wr   = wv >> 2;           // 0..1  (M half)
  const int wc   = wv & 3;            // 0..3  (N quarter)
  const int fr   = lane & 15;
  const int fq   = lane >> 4;

  // bijective XCD swizzle (nwg % 8 == 0 by construction)
  const int nwg = gridDim.x;
  const int cpx = nwg >> 3;
  const int wg  = (blockIdx.x & 7) * cpx + (blockIdx.x >> 3);
  const int bm = wg / nbn, bn = wg % nbn;

  const unsigned short* Ag = A  + (size_t)bm * 256 * K;
  const unsigned short* Bg = Bt + (size_t)bn * 256 * K;

  // staging: thread -> (row = tid>>2 [+128], 16B chunk = tid&3), LDS linear,
  // global column chunk XOR-swizzled (involution, same XOR applied on read)
  const int r0  = tid >> 2;           // rows 0..127
  const int r1  = 128 + r0;           // rows 128..255
  const int c0  = tid & 3;
  const int cs0 = c0 ^ ((r0 >> 1) & 3);
  const int cs1 = c0 ^ ((r1 >> 1) & 3);
  const int ld0 = tid * 8;            // ushort offset (16B per thread)
  const int ld1 = (512 + tid) * 8;

#define STAGE(ARR, srcp, kofs)                                                           \
  do {                                                                                   \
    __builtin_amdgcn_global_load_lds(                                                    \
      (const __attribute__((address_space(1))) void*)((srcp) + (size_t)r0*K + (kofs) + cs0*8), \
      (__attribute__((address_space(3))) void*)(&(ARR)[ld0]), 16, 0, 0);                 \
    __builtin_amdgcn_global_load_lds(                                                    \
      (const __attribute__((address_space(1))) void*)((srcp) + (size_t)r1*K + (kofs) + cs1*8), \
      (__attribute__((address_space(3))) void*)(&(ARR)[ld1]), 16, 0, 0);                 \
  } while(0)

  // fragment LDS offsets (ushort units); row-swizzle term identical for all
  // fragment rows of a wave (rows differ by multiples of 16 -> (row>>1)&3 fixed)
  const int swz  = fq ^ ((fr >> 1) & 3);
  const int offA = (wr*128 + fr) * 32 + swz * 8;
  const int offB = (wc*64  + fr) * 32 + swz * 8;

  f32x4 acc[8][4];
#pragma unroll
  for (int i = 0; i < 8; ++i)
#pragma unroll
    for (int j = 0; j < 4; ++j) acc[i][j] = {0.f,0.f,0.f,0.f};

  bf16x8 afr[4], bfr[4];

#define PHASE(PAR, KH, MH, STAGE_STMT, TAIL_WAIT)                          \
  do {                                                                     \
    _Pragma("unroll")                                                      \
    for (int m2 = 0; m2 < 4; ++m2)                                         \
      afr[m2] = *(const bf16x8*)(&sA[PAR][KH][offA + ((MH)*4+m2)*512]);    \
    if ((MH) == 0) {                                                       \
      _Pragma("unroll")                                                    \
      for (int n2 = 0; n2 < 4; ++n2)                                       \
        bfr[n2] = *(const bf16x8*)(&sB[PAR][KH][offB + n2*512]);           \
    }                                                                      \
    STAGE_STMT;                                                            \
    BARRIER();                                                             \
    __builtin_amdgcn_s_setprio(1);                                         \
    _Pragma("unroll")                                                      \
    for (int n2 = 0; n2 < 4; ++n2)                                         \
      _Pragma("unroll")                                                    \
      for (int m2 = 0; m2 < 4; ++m2)                                       \
        acc[(MH)*4+m2][n2] = __builtin_amdgcn_mfma_f32_16x16x32_bf16(      \
            afr[m2], bfr[n2], acc[(MH)*4+m2][n2], 0, 0, 0);                \
    __builtin_amdgcn_s_setprio(0);                                         \
    TAIL_WAIT;                                                             \
    BARRIER();                                                             \
  } while(0)

  const int npairs = K >> 7;          // tiles = K/64, pairs of (even par0, odd par1)

  // prologue: stage all 4 half-tiles of tile 0 into parity 0
  STAGE(sA[0][0], Ag, 0);
  STAGE(sB[0][0], Bg, 0);
  STAGE(sA[0][1], Ag, 32);
  STAGE(sB[0][1], Bg, 32);
  WAIT_VM4();                 // kh0 halves landed; kh1 (4 loads) still in flight
  BARRIER();

  for (int i = 0; i < npairs - 1; ++i){
    const int kbO = ((i << 1) + 1) << 6;   // odd tile k-base
    const int kbE = ((i << 1) + 2) << 6;   // next even tile k-base
    PHASE(0, 0, 0, STAGE(sA[1][0], Ag, kbO),      );
    PHASE(0, 0, 1, STAGE(sB[1][0], Bg, kbO),      WAIT_VM4());  // kh1(2i) landed
    PHASE(0, 1, 0, STAGE(sA[1][1], Ag, kbO + 32), );
    PHASE(0, 1, 1, STAGE(sB[1][1], Bg, kbO + 32), WAIT_VM4());  // kh0(2i+1) landed
    PHASE(1, 0, 0, STAGE(sA[0][0], Ag, kbE),      );
    PHASE(1, 0, 1, STAGE(sB[0][0], Bg, kbE),      WAIT_VM4());  // kh1(2i+1) landed
    PHASE(1, 1, 0, STAGE(sA[0][1], Ag, kbE + 32), );
    PHASE(1, 1, 1, STAGE(sB[0][1], Bg, kbE + 32), WAIT_VM4());  // kh0(2i+2) landed
  }
  PHASE(0, 0, 0, STAGE(sA[1][0], Ag, K - 64), );
  PHASE(0, 0, 1, STAGE(sB[1][0], Bg, K - 64), WAIT_VM4());
  PHASE(0, 1, 0, STAGE(sA[1][1], Ag, K - 32), );
  PHASE(0, 1, 1, STAGE(sB[1][1], Bg, K - 32), WAIT_VM4());
  PHASE(1, 0, 0, , );
  PHASE(1, 0, 1, , WAIT_VM0());   // kh1(last) landed
  PHASE(1, 1, 0, , );
  PHASE(1, 1, 1, , );

  // ---------- epilogue (line-coalesced: ni innermost) ----------
  const int nb = bn*256 + wc*64;
  const int mb = bm*256 + wr*128;
  float bsv[4];
#pragma unroll
  for (int ni = 0; ni < 4; ++ni) bsv[ni] = bias[nb + ni*16 + fr];

  if (EPI == 0){
    const bool isV = (nb >= D_DIM);   // uniform per block (256-col tiles)
    unsigned short* dst = isV ? (outV + (nb - D_DIM)) : (outU + nb);
#pragma unroll
    for (int mi = 0; mi < 8; ++mi){
#pragma unroll
      for (int j = 0; j < 4; ++j){
        const int m = mb + mi*16 + fq*4 + j;
        unsigned short* row = dst + (size_t)m*D_DIM + fr;
#pragma unroll
        for (int ni = 0; ni < 4; ++ni){
          float cv = acc[mi][ni][j] + bsv[ni];
          row[ni*16] = f2bf(isV ? siluf_(cv) : cv);
        }
      }
    }
  } else {
    // h = acc + bias + resid stored as bf16 (halves GEMM2 write AND LN read)
#pragma unroll
    for (int mi = 0; mi < 8; ++mi){
#pragma unroll
      for (int j = 0; j < 4; ++j){
        const int m = mb + mi*16 + fq*4 + j;
        const float* rrow = resid + (size_t)m*D_DIM + nb + fr;
        unsigned short* orow = outU + (size_t)m*D_DIM + nb + fr;
#pragma unroll
        for (int ni = 0; ni < 4; ++ni)
          orow[ni*16] = f2bf(acc[mi][ni][j] + bsv[ni] + rrow[ni*16]);
      }
    }
  }
#undef PHASE
#undef STAGE
#undef BARRIER
#undef FENCE
#undef WAIT_VM4
#undef WAIT_VM0
}

// ---------------- fused conv + chunked SSM scan ----------------
// Pass A: per-chunk local scan from h=0, write carry h_end[b][c][d]
__global__ __launch_bounds__(256) void scan_a(
    const unsigned short* __restrict__ v,
    const float* __restrict__ conv_w, const float* __restrict__ conv_b,
    const float* __restrict__ logit_a, const float* __restrict__ ssm_b,
    float* __restrict__ hend)
{
  const int b = blockIdx.x / NCHUNK;
  const int c = blockIdx.x % NCHUNK;
  const int d0 = threadIdx.x * 4;
  const int t0 = c * CLEN;
  const unsigned short* vb = v + (size_t)b * T_DIM * D_DIM;

  float w0[4], w1[4], w2[4], av[4], bv[4], cb[4];
#pragma unroll
  for (int i=0;i<4;i++){
    w0[i] = conv_w[(d0+i)*3+0];
    w1[i] = conv_w[(d0+i)*3+1];
    w2[i] = conv_w[(d0+i)*3+2];
    cb[i] = conv_b[d0+i];
    av[i] = sigmoidf_(logit_a[d0+i]);
    bv[i] = ssm_b[d0+i];
  }
  float vm1[4], v0[4], h[4] = {0.f,0.f,0.f,0.f};
  if (t0 == 0){
#pragma unroll
    for (int i=0;i<4;i++) vm1[i]=0.f;
  } else {
    ushort4 u = *(const ushort4*)(vb + (size_t)(t0-1)*D_DIM + d0);
    vm1[0]=bf2f(u.x); vm1[1]=bf2f(u.y); vm1[2]=bf2f(u.z); vm1[3]=bf2f(u.w);
  }
  {
    ushort4 u = *(const ushort4*)(vb + (size_t)t0*D_DIM + d0);
    v0[0]=bf2f(u.x); v0[1]=bf2f(u.y); v0[2]=bf2f(u.z); v0[3]=bf2f(u.w);
  }
#pragma unroll 8
  for (int t = t0; t < t0 + CLEN; ++t){
    float vp1[4];
    if (t + 1 < T_DIM){
      ushort4 u = *(const ushort4*)(vb + (size_t)(t+1)*D_DIM + d0);
      vp1[0]=bf2f(u.x); vp1[1]=bf2f(u.y); vp1[2]=bf2f(u.z); vp1[3]=bf2f(u.w);
    } else { vp1[0]=vp1[1]=vp1[2]=vp1[3]=0.f; }
#pragma unroll
    for (int i=0;i<4;i++){
      float vl = w0[i]*vm1[i] + w1[i]*v0[i] + w2[i]*vp1[i] + cb[i];
      h[i] = av[i]*h[i] + bv[i]*vl;
      vm1[i]=v0[i]; v0[i]=vp1[i];
    }
  }
  float* he = hend + ((size_t)b*NCHUNK + c)*D_DIM + d0;
#pragma unroll
  for (int i=0;i<4;i++) he[i] = h[i];
}

// combine carries across chunks: h_init[c] = aL*h_init[c-1] + h_end[c-1].
// batch-8 register prefetch breaks the 128-deep dependent-load chain.
__global__ void scan_fix(const float* __restrict__ hend, const float* __restrict__ logit_a,
                         float* __restrict__ hinit)
{
  int idx = blockIdx.x*blockDim.x + threadIdx.x;   // b*D + d
  if (idx >= B_DIM*D_DIM) return;
  const int b = idx / D_DIM, d = idx % D_DIM;
  const float a  = sigmoidf_(logit_a[d]);
  const float aL = __powf(a, (float)CLEN);
  const float* hep = hend  + (size_t)b*NCHUNK*D_DIM + d;
  float*       hip = hinit + (size_t)b*NCHUNK*D_DIM + d;
  float h = 0.f;
  for (int cb = 0; cb < NCHUNK; cb += 8){
    float buf[8];
#pragma unroll
    for (int j = 0; j < 8; ++j)
      buf[j] = hep[(size_t)(cb + j)*D_DIM];
#pragma unroll
    for (int j = 0; j < 8; ++j){
      hip[(size_t)(cb + j)*D_DIM] = h;
      h = aL*h + buf[j];
    }
  }
}

// Pass C: replay with correct h0; y = c*h + d*vl; gated = u * silu(y) -> bf16
__global__ __launch_bounds__(256) void scan_c(
    const unsigned short* __restrict__ v,
    const unsigned short* __restrict__ ubuf,
    const float* __restrict__ conv_w, const float* __restrict__ conv_b,
    const float* __restrict__ logit_a, const float* __restrict__ ssm_b,
    const float* __restrict__ ssm_c, const float* __restrict__ ssm_d,
    const float* __restrict__ hinit,
    unsigned short* __restrict__ gated)
{
  const int b = blockIdx.x / NCHUNK;
  const int c = blockIdx.x % NCHUNK;
  const int d0 = threadIdx.x * 4;
  const int t0 = c * CLEN;
  const unsigned short* vb = v    + (size_t)b * T_DIM * D_DIM;
  const unsigned short* ub = ubuf + (size_t)b * T_DIM * D_DIM;
  unsigned short* gb       = gated+ (size_t)b * T_DIM * D_DIM;

  float w0[4], w1[4], w2[4], av[4], bv[4], cb[4], scv[4], sdv[4], h[4];
#pragma unroll
  for (int i=0;i<4;i++){
    w0[i] = conv_w[(d0+i)*3+0];
    w1[i] = conv_w[(d0+i)*3+1];
    w2[i] = conv_w[(d0+i)*3+2];
    cb[i] = conv_b[d0+i];
    av[i] = sigmoidf_(logit_a[d0+i]);
    bv[i] = ssm_b[d0+i];
    scv[i] = ssm_c[d0+i];
    sdv[i] = ssm_d[d0+i];
    h[i] = hinit[((size_t)b*NCHUNK + c)*D_DIM + d0 + i];
  }
  float vm1[4], v0[4];
  if (t0 == 0){
#pragma unroll
    for (int i=0;i<4;i++) vm1[i]=0.f;
  } else {
    ushort4 u = *(const ushort4*)(vb + (size_t)(t0-1)*D_DIM + d0);
    vm1[0]=bf2f(u.x); vm1[1]=bf2f(u.y); vm1[2]=bf2f(u.z); vm1[3]=bf2f(u.w);
  }
  {
    ushort4 u = *(const ushort4*)(vb + (size_t)t0*D_DIM + d0);
    v0[0]=bf2f(u.x); v0[1]=bf2f(u.y); v0[2]=bf2f(u.z); v0[3]=bf2f(u.w);
  }
#pragma unroll 8
  for (int t = t0; t < t0 + CLEN; ++t){
    float vp1[4];
    if (t + 1 < T_DIM){
      ushort4 u = *(const ushort4*)(vb + (size_t)(t+1)*D_DIM + d0);
      vp1[0]=bf2f(u.x); vp1[1]=bf2f(u.y); vp1[2]=bf2f(u.z); vp1[3]=bf2f(u.w);
    } else { vp1[0]=vp1[1]=vp1[2]=vp1[3]=0.f; }
    ushort4 uu = *(const ushort4*)(ub + (size_t)t*D_DIM + d0);
    float uf[4] = { bf2f(uu.x), bf2f(uu.y), bf2f(uu.z), bf2f(uu.w) };
    ushort4 go;
    unsigned short gtmp[4];
#pragma unroll
    for (int i=0;i<4;i++){
      float vl = w0[i]*vm1[i] + w1[i]*v0[i] + w2[i]*vp1[i] + cb[i];
      h[i] = av[i]*h[i] + bv[i]*vl;
      float y = scv[i]*h[i] + sdv[i]*vl;
      gtmp[i] = f2bf(uf[i] * siluf_(y));
      vm1[i]=v0[i]; v0[i]=vp1[i];
    }
    go.x=gtmp[0]; go.y=gtmp[1]; go.z=gtmp[2]; go.w=gtmp[3];
    *(ushort4*)(gb + (size_t)t*D_DIM + d0) = go;
  }
}

// ---------------- LayerNorm (bf16 h in, fp32 out; one block per row) ----------------
__global__ __launch_bounds__(256) void ln_kernel(
    const unsigned short* __restrict__ hb, float* __restrict__ out,
    const float* __restrict__ lw, const float* __restrict__ lb)
{
  __shared__ float rs[4], rq[4];
  const int row = blockIdx.x;
  const int tid = threadIdx.x;
  const unsigned short* p = hb + (size_t)row * D_DIM;
  ushort4 u = *(const ushort4*)(p + tid*4);
  float x0 = bf2f(u.x), x1 = bf2f(u.y), x2 = bf2f(u.z), x3 = bf2f(u.w);
  float s = x0 + x1 + x2 + x3;
  float q = x0*x0 + x1*x1 + x2*x2 + x3*x3;
#pragma unroll
  for (int off = 32; off > 0; off >>= 1){
    s += __shfl_down(s, off, 64);
    q += __shfl_down(q, off, 64);
  }
  const int wv = tid >> 6;
  if ((tid & 63) == 0){ rs[wv] = s; rq[wv] = q; }
  __syncthreads();
  const float ts = rs[0]+rs[1]+rs[2]+rs[3];
  const float tq = rq[0]+rq[1]+rq[2]+rq[3];
  const float mu  = ts * (1.f/(float)D_DIM);
  const float var = tq * (1.f/(float)D_DIM) - mu*mu;
  const float inv = rsqrtf(var + LN_EPS);
  const float4 w4 = *(const float4*)(lw + tid*4);
  const float4 b4 = *(const float4*)(lb + tid*4);
  float4 o;
  o.x = (x0-mu)*inv*w4.x + b4.x;
  o.y = (x1-mu)*inv*w4.y + b4.y;
  o.z = (x2-mu)*inv*w4.z + b4.z;
  o.w = (x3-mu)*inv*w4.w + b4.w;
  *(float4*)(out + (size_t)row*D_DIM + tid*4) = o;
}

// ---------------- launch ----------------
extern "C" void kernel_launch(void* const* d_in, const int* in_sizes, int n_in,
                              void* d_out, int out_size, void* d_ws, size_t ws_size,
                              hipStream_t stream)
{
  const float* x     = (const float*)d_in[0];
  const float* w1    = (const float*)d_in[1];
  const float* b1    = (const float*)d_in[2];
  const float* convw = (const float*)d_in[3];
  const float* convb = (const float*)d_in[4];
  const float* la    = (const float*)d_in[5];
  const float* sb    = (const float*)d_in[6];
  const float* sc    = (const float*)d_in[7];
  const float* sd    = (const float*)d_in[8];
  const float* w2    = (const float*)d_in[9];
  const float* b2    = (const float*)d_in[10];
  const float* lw    = (const float*)d_in[11];
  const float* lb    = (const float*)d_in[12];
  float* out = (float*)d_out;

  char* ws = (char*)d_ws;
  unsigned short* xb    = (unsigned short*)(ws + 0);          // x bf16; reused as gated
  unsigned short* ubf   = (unsigned short*)(ws + 67108864);   // u; reused as h (bf16) after scan_c
  unsigned short* vbf   = (unsigned short*)(ws + 134217728);  // v (silu'd)
  unsigned short* w1t   = (unsigned short*)(ws + 201326592);
  unsigned short* w2t   = (unsigned short*)(ws + 205520896);
  float*          hend  = (float*)(ws + 207618048);
  float*          hinit = (float*)(ws + 211812352);

  cvt_f32_bf16<<<2048, 256, 0, stream>>>(x, xb, BT_DIM*D_DIM);
  cvt_transpose<<<(D_DIM/32)*(TWO_D/32), 256, 0, stream>>>(w1, w1t, D_DIM, TWO_D);
  cvt_transpose<<<(D_DIM/32)*(D_DIM/32), 256, 0, stream>>>(w2, w2t, D_DIM, D_DIM);

  // GEMM1: M=32768, N=2048, K=1024 -> 1024 blocks
  gemm256<0><<<dim3((BT_DIM/256)*(TWO_D/256)), 512, 0, stream>>>(
      xb, w1t, b1, nullptr, ubf, vbf, D_DIM, TWO_D/256);

  scan_a<<<B_DIM*NCHUNK, 256, 0, stream>>>(vbf, convw, convb, la, sb, hend);
  scan_fix<<<(B_DIM*D_DIM + 255)/256, 256, 0, stream>>>(hend, la, hinit);
  scan_c<<<B_DIM*NCHUNK, 256, 0, stream>>>(vbf, ubf, convw, convb, la, sb, sc, sd, hinit, xb);

  // GEMM2: M=32768, N=1024, K=1024 -> 512 blocks; h (bf16) -> ubf
  gemm256<1><<<dim3((BT_DIM/256)*(D_DIM/256)), 512, 0, stream>>>(
      xb, w2t, b2, x, ubf, nullptr, D_DIM, D_DIM/256);

  ln_kernel<<<BT_DIM, 256, 0, stream>>>(ubf, out, lw, lb);
}

// Round 17
// 392.103 us; speedup vs baseline: 6.9368x; 1.0035x over previous
//
#include <hip/hip_runtime.h>
#include <cstdint>
#include <cstddef>

#define D_DIM   1024
#define TWO_D   2048
#define B_DIM   8
#define T_DIM   4096
#define BT_DIM  (B_DIM*T_DIM)     // 32768 rows
#define LN_EPS  1e-5f
#define NCHUNK  128
#define CLEN    (T_DIM/NCHUNK)    // 32 steps per chunk

typedef __attribute__((ext_vector_type(8))) short bf16x8;
typedef __attribute__((ext_vector_type(4))) float f32x4;

__device__ __forceinline__ float bf2f(unsigned short u){
  union { unsigned int i; float f; } c; c.i = ((unsigned int)u) << 16; return c.f;
}
__device__ __forceinline__ unsigned short f2bf(float f){
  union { float f; unsigned int i; } c; c.f = f;
  unsigned int x = c.i;
  return (unsigned short)((x + 0x7fffu + ((x >> 16) & 1u)) >> 16);
}
__device__ __forceinline__ float sigmoidf_(float x){ return 1.f/(1.f+__expf(-x)); }
__device__ __forceinline__ float siluf_(float x){ return x/(1.f+__expf(-x)); }

// ---------------- conversion kernels ----------------

__global__ void cvt_f32_bf16(const float* __restrict__ in, unsigned short* __restrict__ out, int n){
  int i = (blockIdx.x*blockDim.x + threadIdx.x)*4;
  const int stride = gridDim.x*blockDim.x*4;
  for (; i + 3 < n; i += stride){
    float4 f = *(const float4*)(in + i);
    ushort4 o; o.x=f2bf(f.x); o.y=f2bf(f.y); o.z=f2bf(f.z); o.w=f2bf(f.w);
    *(ushort4*)(out + i) = o;
  }
}

// LDS-tiled transpose: W (rows x cols, fp32) -> Wt (cols x rows, bf16).
__global__ __launch_bounds__(256) void cvt_transpose(
    const float* __restrict__ W, unsigned short* __restrict__ Wt,
    int rows, int cols)
{
  __shared__ float tile[32][33];
  const int tx = threadIdx.x & 31;
  const int ty = threadIdx.x >> 5;        // 0..7
  const int tpc = cols >> 5;
  const int bc = blockIdx.x % tpc;
  const int br = blockIdx.x / tpc;
  const int gc = bc*32 + tx;
  const int gr = br*32;
#pragma unroll
  for (int i = 0; i < 32; i += 8)
    tile[ty + i][tx] = W[(size_t)(gr + ty + i)*cols + gc];
  __syncthreads();
#pragma unroll
  for (int i = 0; i < 32; i += 8)
    Wt[(size_t)(bc*32 + ty + i)*rows + gr + tx] = f2bf(tile[tx][ty + i]);
}

// ---------------- 256x256 8-phase GEMM (R17: mid-phase barrier removed) ----------------
// R17 = R16 minus the mid-phase BARRIER. Hazard audit: frag reads touch parity
// P, STAGE DMAs write parity P^1 (disjoint); cross-tile WAR/RAW is fully
// covered by the END-of-phase vm-wait + barrier chain. The mid-barrier only
// enforced wave lockstep (all reads drain before any MFMA = the convoy that
// capped MfmaUtil at 33%). Without it, waves stagger within a phase: one
// wave's MFMA overlaps another's ds_reads (m114 wave-level overlap), bounded
// by the end barrier. Literal parity, counted vmcnt(4), setprio, XOR swizzle,
// XCD swizzle unchanged.
// EPI 0: uv = A@B + bias; n<1024 -> u (bf16), n>=1024 -> silu -> v (bf16)
// EPI 1: h = A@B + bias + resid -> outU (bf16)
template<int EPI>
__global__ __launch_bounds__(512, 2) void gemm256(
    const unsigned short* __restrict__ A,    // M x K bf16
    const unsigned short* __restrict__ Bt,   // N x K bf16
    const float* __restrict__ bias,          // N
    const float* __restrict__ resid,         // M x 1024 fp32 (EPI 1)
    unsigned short* __restrict__ outU,
    unsigned short* __restrict__ outV,
    const int K, const int nbn)
{
  __shared__ __align__(16) unsigned short sA[2][2][8192];
  __shared__ __align__(16) unsigned short sB[2][2][8192];

#define BARRIER()   __builtin_amdgcn_s_barrier()
#define FENCE()     __builtin_amdgcn_sched_barrier(0)
#define WAIT_VM4()  do { asm volatile("s_waitcnt vmcnt(4)"); FENCE(); } while(0)
#define WAIT_VM0()  do { asm volatile("s_waitcnt vmcnt(0)"); FENCE(); } while(0)

  const int tid  = threadIdx.x;
  const int lane = tid & 63;
  const int wv   = tid >> 6;          // 0..7
  const int wr   = wv >> 2;           // 0..1  (M half)
  const int wc   = wv & 3;            // 0..3  (N quarter)
  const int fr   = lane & 15;
  const int fq   = lane >> 4;

  // bijective XCD swizzle (nwg % 8 == 0 by construction)
  const int nwg = gridDim.x;
  const int cpx = nwg >> 3;
  const int wg  = (blockIdx.x & 7) * cpx + (blockIdx.x >> 3);
  const int bm = wg / nbn, bn = wg % nbn;

  const unsigned short* Ag = A  + (size_t)bm * 256 * K;
  const unsigned short* Bg = Bt + (size_t)bn * 256 * K;

  // staging: thread -> (row = tid>>2 [+128], 16B chunk = tid&3), LDS linear,
  // global column chunk XOR-swizzled (involution, same XOR applied on read)
  const int r0  = tid >> 2;           // rows 0..127
  const int r1  = 128 + r0;           // rows 128..255
  const int c0  = tid & 3;
  const int cs0 = c0 ^ ((r0 >> 1) & 3);
  const int cs1 = c0 ^ ((r1 >> 1) & 3);
  const int ld0 = tid * 8;            // ushort offset (16B per thread)
  const int ld1 = (512 + tid) * 8;

#define STAGE(ARR, srcp, kofs)                                                           \
  do {                                                                                   \
    __builtin_amdgcn_global_load_lds(                                                    \
      (const __attribute__((address_space(1))) void*)((srcp) + (size_t)r0*K + (kofs) + cs0*8), \
      (__attribute__((address_space(3))) void*)(&(ARR)[ld0]), 16, 0, 0);                 \
    __builtin_amdgcn_global_load_lds(                                                    \
      (const __attribute__((address_space(1))) void*)((srcp) + (size_t)r1*K + (kofs) + cs1*8), \
      (__attribute__((address_space(3))) void*)(&(ARR)[ld1]), 16, 0, 0);                 \
  } while(0)

  // fragment LDS offsets (ushort units); row-swizzle term identical for all
  // fragment rows of a wave (rows differ by multiples of 16 -> (row>>1)&3 fixed)
  const int swz  = fq ^ ((fr >> 1) & 3);
  const int offA = (wr*128 + fr) * 32 + swz * 8;
  const int offB = (wc*64  + fr) * 32 + swz * 8;

  f32x4 acc[8][4];
#pragma unroll
  for (int i = 0; i < 8; ++i)
#pragma unroll
    for (int j = 0; j < 4; ++j) acc[i][j] = {0.f,0.f,0.f,0.f};

  bf16x8 afr[4], bfr[4];

  // PHASE: frag reads + optional stage + MFMA (no mid barrier — waves stagger),
  // then counted tail vm-wait + END barrier (the only sync point per phase).
#define PHASE(PAR, KH, MH, STAGE_STMT, TAIL_WAIT)                          \
  do {                                                                     \
    _Pragma("unroll")                                                      \
    for (int m2 = 0; m2 < 4; ++m2)                                         \
      afr[m2] = *(const bf16x8*)(&sA[PAR][KH][offA + ((MH)*4+m2)*512]);    \
    if ((MH) == 0) {                                                       \
      _Pragma("unroll")                                                    \
      for (int n2 = 0; n2 < 4; ++n2)                                       \
        bfr[n2] = *(const bf16x8*)(&sB[PAR][KH][offB + n2*512]);           \
    }                                                                      \
    STAGE_STMT;                                                            \
    __builtin_amdgcn_s_setprio(1);                                         \
    _Pragma("unroll")                                                      \
    for (int n2 = 0; n2 < 4; ++n2)                                         \
      _Pragma("unroll")                                                    \
      for (int m2 = 0; m2 < 4; ++m2)                                       \
        acc[(MH)*4+m2][n2] = __builtin_amdgcn_mfma_f32_16x16x32_bf16(      \
            afr[m2], bfr[n2], acc[(MH)*4+m2][n2], 0, 0, 0);                \
    __builtin_amdgcn_s_setprio(0);                                         \
    TAIL_WAIT;                                                             \
    BARRIER();                                                             \
  } while(0)

  const int npairs = K >> 7;          // tiles = K/64, pairs of (even par0, odd par1)

  // prologue: stage all 4 half-tiles of tile 0 into parity 0
  STAGE(sA[0][0], Ag, 0);
  STAGE(sB[0][0], Bg, 0);
  STAGE(sA[0][1], Ag, 32);
  STAGE(sB[0][1], Bg, 32);
  WAIT_VM4();                 // kh0 halves landed; kh1 (4 loads) still in flight
  BARRIER();

  for (int i = 0; i < npairs - 1; ++i){
    const int kbO = ((i << 1) + 1) << 6;   // odd tile k-base
    const int kbE = ((i << 1) + 2) << 6;   // next even tile k-base
    PHASE(0, 0, 0, STAGE(sA[1][0], Ag, kbO),      );
    PHASE(0, 0, 1, STAGE(sB[1][0], Bg, kbO),      WAIT_VM4());  // kh1(2i) landed
    PHASE(0, 1, 0, STAGE(sA[1][1], Ag, kbO + 32), );
    PHASE(0, 1, 1, STAGE(sB[1][1], Bg, kbO + 32), WAIT_VM4());  // kh0(2i+1) landed
    PHASE(1, 0, 0, STAGE(sA[0][0], Ag, kbE),      );
    PHASE(1, 0, 1, STAGE(sB[0][0], Bg, kbE),      WAIT_VM4());  // kh1(2i+1) landed
    PHASE(1, 1, 0, STAGE(sA[0][1], Ag, kbE + 32), );
    PHASE(1, 1, 1, STAGE(sB[0][1], Bg, kbE + 32), WAIT_VM4());  // kh0(2i+2) landed
  }
  PHASE(0, 0, 0, STAGE(sA[1][0], Ag, K - 64), );
  PHASE(0, 0, 1, STAGE(sB[1][0], Bg, K - 64), WAIT_VM4());
  PHASE(0, 1, 0, STAGE(sA[1][1], Ag, K - 32), );
  PHASE(0, 1, 1, STAGE(sB[1][1], Bg, K - 32), WAIT_VM4());
  PHASE(1, 0, 0, , );
  PHASE(1, 0, 1, , WAIT_VM0());   // kh1(last) landed
  PHASE(1, 1, 0, , );
  PHASE(1, 1, 1, , );

  // ---------- epilogue (line-coalesced: ni innermost) ----------
  const int nb = bn*256 + wc*64;
  const int mb = bm*256 + wr*128;
  float bsv[4];
#pragma unroll
  for (int ni = 0; ni < 4; ++ni) bsv[ni] = bias[nb + ni*16 + fr];

  if (EPI == 0){
    const bool isV = (nb >= D_DIM);   // uniform per block (256-col tiles)
    unsigned short* dst = isV ? (outV + (nb - D_DIM)) : (outU + nb);
#pragma unroll
    for (int mi = 0; mi < 8; ++mi){
#pragma unroll
      for (int j = 0; j < 4; ++j){
        const int m = mb + mi*16 + fq*4 + j;
        unsigned short* row = dst + (size_t)m*D_DIM + fr;
#pragma unroll
        for (int ni = 0; ni < 4; ++ni){
          float cv = acc[mi][ni][j] + bsv[ni];
          row[ni*16] = f2bf(isV ? siluf_(cv) : cv);
        }
      }
    }
  } else {
    // h = acc + bias + resid stored as bf16 (halves GEMM2 write AND LN read)
#pragma unroll
    for (int mi = 0; mi < 8; ++mi){
#pragma unroll
      for (int j = 0; j < 4; ++j){
        const int m = mb + mi*16 + fq*4 + j;
        const float* rrow = resid + (size_t)m*D_DIM + nb + fr;
        unsigned short* orow = outU + (size_t)m*D_DIM + nb + fr;
#pragma unroll
        for (int ni = 0; ni < 4; ++ni)
          orow[ni*16] = f2bf(acc[mi][ni][j] + bsv[ni] + rrow[ni*16]);
      }
    }
  }
#undef PHASE
#undef STAGE
#undef BARRIER
#undef FENCE
#undef WAIT_VM4
#undef WAIT_VM0
}

// ---------------- fused conv + chunked SSM scan ----------------
// Pass A: per-chunk local scan from h=0, write carry h_end[b][c][d]
__global__ __launch_bounds__(256) void scan_a(
    const unsigned short* __restrict__ v,
    const float* __restrict__ conv_w, const float* __restrict__ conv_b,
    const float* __restrict__ logit_a, const float* __restrict__ ssm_b,
    float* __restrict__ hend)
{
  const int b = blockIdx.x / NCHUNK;
  const int c = blockIdx.x % NCHUNK;
  const int d0 = threadIdx.x * 4;
  const int t0 = c * CLEN;
  const unsigned short* vb = v + (size_t)b * T_DIM * D_DIM;

  float w0[4], w1[4], w2[4], av[4], bv[4], cb[4];
#pragma unroll
  for (int i=0;i<4;i++){
    w0[i] = conv_w[(d0+i)*3+0];
    w1[i] = conv_w[(d0+i)*3+1];
    w2[i] = conv_w[(d0+i)*3+2];
    cb[i] = conv_b[d0+i];
    av[i] = sigmoidf_(logit_a[d0+i]);
    bv[i] = ssm_b[d0+i];
  }
  float vm1[4], v0[4], h[4] = {0.f,0.f,0.f,0.f};
  if (t0 == 0){
#pragma unroll
    for (int i=0;i<4;i++) vm1[i]=0.f;
  } else {
    ushort4 u = *(const ushort4*)(vb + (size_t)(t0-1)*D_DIM + d0);
    vm1[0]=bf2f(u.x); vm1[1]=bf2f(u.y); vm1[2]=bf2f(u.z); vm1[3]=bf2f(u.w);
  }
  {
    ushort4 u = *(const ushort4*)(vb + (size_t)t0*D_DIM + d0);
    v0[0]=bf2f(u.x); v0[1]=bf2f(u.y); v0[2]=bf2f(u.z); v0[3]=bf2f(u.w);
  }
#pragma unroll 8
  for (int t = t0; t < t0 + CLEN; ++t){
    float vp1[4];
    if (t + 1 < T_DIM){
      ushort4 u = *(const ushort4*)(vb + (size_t)(t+1)*D_DIM + d0);
      vp1[0]=bf2f(u.x); vp1[1]=bf2f(u.y); vp1[2]=bf2f(u.z); vp1[3]=bf2f(u.w);
    } else { vp1[0]=vp1[1]=vp1[2]=vp1[3]=0.f; }
#pragma unroll
    for (int i=0;i<4;i++){
      float vl = w0[i]*vm1[i] + w1[i]*v0[i] + w2[i]*vp1[i] + cb[i];
      h[i] = av[i]*h[i] + bv[i]*vl;
      vm1[i]=v0[i]; v0[i]=vp1[i];
    }
  }
  float* he = hend + ((size_t)b*NCHUNK + c)*D_DIM + d0;
#pragma unroll
  for (int i=0;i<4;i++) he[i] = h[i];
}

// combine carries across chunks: h_init[c] = aL*h_init[c-1] + h_end[c-1].
// batch-8 register prefetch breaks the 128-deep dependent-load chain.
__global__ void scan_fix(const float* __restrict__ hend, const float* __restrict__ logit_a,
                         float* __restrict__ hinit)
{
  int idx = blockIdx.x*blockDim.x + threadIdx.x;   // b*D + d
  if (idx >= B_DIM*D_DIM) return;
  const int b = idx / D_DIM, d = idx % D_DIM;
  const float a  = sigmoidf_(logit_a[d]);
  const float aL = __powf(a, (float)CLEN);
  const float* hep = hend  + (size_t)b*NCHUNK*D_DIM + d;
  float*       hip = hinit + (size_t)b*NCHUNK*D_DIM + d;
  float h = 0.f;
  for (int cb = 0; cb < NCHUNK; cb += 8){
    float buf[8];
#pragma unroll
    for (int j = 0; j < 8; ++j)
      buf[j] = hep[(size_t)(cb + j)*D_DIM];
#pragma unroll
    for (int j = 0; j < 8; ++j){
      hip[(size_t)(cb + j)*D_DIM] = h;
      h = aL*h + buf[j];
    }
  }
}

// Pass C: replay with correct h0; y = c*h + d*vl; gated = u * silu(y) -> bf16
__global__ __launch_bounds__(256) void scan_c(
    const unsigned short* __restrict__ v,
    const unsigned short* __restrict__ ubuf,
    const float* __restrict__ conv_w, const float* __restrict__ conv_b,
    const float* __restrict__ logit_a, const float* __restrict__ ssm_b,
    const float* __restrict__ ssm_c, const float* __restrict__ ssm_d,
    const float* __restrict__ hinit,
    unsigned short* __restrict__ gated)
{
  const int b = blockIdx.x / NCHUNK;
  const int c = blockIdx.x % NCHUNK;
  const int d0 = threadIdx.x * 4;
  const int t0 = c * CLEN;
  const unsigned short* vb = v    + (size_t)b * T_DIM * D_DIM;
  const unsigned short* ub = ubuf + (size_t)b * T_DIM * D_DIM;
  unsigned short* gb       = gated+ (size_t)b * T_DIM * D_DIM;

  float w0[4], w1[4], w2[4], av[4], bv[4], cb[4], scv[4], sdv[4], h[4];
#pragma unroll
  for (int i=0;i<4;i++){
    w0[i] = conv_w[(d0+i)*3+0];
    w1[i] = conv_w[(d0+i)*3+1];
    w2[i] = conv_w[(d0+i)*3+2];
    cb[i] = conv_b[d0+i];
    av[i] = sigmoidf_(logit_a[d0+i]);
    bv[i] = ssm_b[d0+i];
    scv[i] = ssm_c[d0+i];
    sdv[i] = ssm_d[d0+i];
    h[i] = hinit[((size_t)b*NCHUNK + c)*D_DIM + d0 + i];
  }
  float vm1[4], v0[4];
  if (t0 == 0){
#pragma unroll
    for (int i=0;i<4;i++) vm1[i]=0.f;
  } else {
    ushort4 u = *(const ushort4*)(vb + (size_t)(t0-1)*D_DIM + d0);
    vm1[0]=bf2f(u.x); vm1[1]=bf2f(u.y); vm1[2]=bf2f(u.z); vm1[3]=bf2f(u.w);
  }
  {
    ushort4 u = *(const ushort4*)(vb + (size_t)t0*D_DIM + d0);
    v0[0]=bf2f(u.x); v0[1]=bf2f(u.y); v0[2]=bf2f(u.z); v0[3]=bf2f(u.w);
  }
#pragma unroll 8
  for (int t = t0; t < t0 + CLEN; ++t){
    float vp1[4];
    if (t + 1 < T_DIM){
      ushort4 u = *(const ushort4*)(vb + (size_t)(t+1)*D_DIM + d0);
      vp1[0]=bf2f(u.x); vp1[1]=bf2f(u.y); vp1[2]=bf2f(u.z); vp1[3]=bf2f(u.w);
    } else { vp1[0]=vp1[1]=vp1[2]=vp1[3]=0.f; }
    ushort4 uu = *(const ushort4*)(ub + (size_t)t*D_DIM + d0);
    float uf[4] = { bf2f(uu.x), bf2f(uu.y), bf2f(uu.z), bf2f(uu.w) };
    ushort4 go;
    unsigned short gtmp[4];
#pragma unroll
    for (int i=0;i<4;i++){
      float vl = w0[i]*vm1[i] + w1[i]*v0[i] + w2[i]*vp1[i] + cb[i];
      h[i] = av[i]*h[i] + bv[i]*vl;
      float y = scv[i]*h[i] + sdv[i]*vl;
      gtmp[i] = f2bf(uf[i] * siluf_(y));
      vm1[i]=v0[i]; v0[i]=vp1[i];
    }
    go.x=gtmp[0]; go.y=gtmp[1]; go.z=gtmp[2]; go.w=gtmp[3];
    *(ushort4*)(gb + (size_t)t*D_DIM + d0) = go;
  }
}

// ---------------- LayerNorm (bf16 h in, fp32 out; one block per row) ----------------
__global__ __launch_bounds__(256) void ln_kernel(
    const unsigned short* __restrict__ hb, float* __restrict__ out,
    const float* __restrict__ lw, const float* __restrict__ lb)
{
  __shared__ float rs[4], rq[4];
  const int row = blockIdx.x;
  const int tid = threadIdx.x;
  const unsigned short* p = hb + (size_t)row * D_DIM;
  ushort4 u = *(const ushort4*)(p + tid*4);
  float x0 = bf2f(u.x), x1 = bf2f(u.y), x2 = bf2f(u.z), x3 = bf2f(u.w);
  float s = x0 + x1 + x2 + x3;
  float q = x0*x0 + x1*x1 + x2*x2 + x3*x3;
#pragma unroll
  for (int off = 32; off > 0; off >>= 1){
    s += __shfl_down(s, off, 64);
    q += __shfl_down(q, off, 64);
  }
  const int wv = tid >> 6;
  if ((tid & 63) == 0){ rs[wv] = s; rq[wv] = q; }
  __syncthreads();
  const float ts = rs[0]+rs[1]+rs[2]+rs[3];
  const float tq = rq[0]+rq[1]+rq[2]+rq[3];
  const float mu  = ts * (1.f/(float)D_DIM);
  const float var = tq * (1.f/(float)D_DIM) - mu*mu;
  const float inv = rsqrtf(var + LN_EPS);
  const float4 w4 = *(const float4*)(lw + tid*4);
  const float4 b4 = *(const float4*)(lb + tid*4);
  float4 o;
  o.x = (x0-mu)*inv*w4.x + b4.x;
  o.y = (x1-mu)*inv*w4.y + b4.y;
  o.z = (x2-mu)*inv*w4.z + b4.z;
  o.w = (x3-mu)*inv*w4.w + b4.w;
  *(float4*)(out + (size_t)row*D_DIM + tid*4) = o;
}

// ---------------- launch ----------------
extern "C" void kernel_launch(void* const* d_in, const int* in_sizes, int n_in,
                              void* d_out, int out_size, void* d_ws, size_t ws_size,
                              hipStream_t stream)
{
  const float* x     = (const float*)d_in[0];
  const float* w1    = (const float*)d_in[1];
  const float* b1    = (const float*)d_in[2];
  const float* convw = (const float*)d_in[3];
  const float* convb = (const float*)d_in[4];
  const float* la    = (const float*)d_in[5];
  const float* sb    = (const float*)d_in[6];
  const float* sc    = (const float*)d_in[7];
  const float* sd    = (const float*)d_in[8];
  const float* w2    = (const float*)d_in[9];
  const float* b2    = (const float*)d_in[10];
  const float* lw    = (const float*)d_in[11];
  const float* lb    = (const float*)d_in[12];
  float* out = (float*)d_out;

  char* ws = (char*)d_ws;
  unsigned short* xb    = (unsigned short*)(ws + 0);          // x bf16; reused as gated
  unsigned short* ubf   = (unsigned short*)(ws + 67108864);   // u; reused as h (bf16) after scan_c
  unsigned short* vbf   = (unsigned short*)(ws + 134217728);  // v (silu'd)
  unsigned short* w1t   = (unsigned short*)(ws + 201326592);
  unsigned short* w2t   = (unsigned short*)(ws + 205520896);
  float*          hend  = (float*)(ws + 207618048);
  float*          hinit = (float*)(ws + 211812352);

  cvt_f32_bf16<<<2048, 256, 0, stream>>>(x, xb, BT_DIM*D_DIM);
  cvt_transpose<<<(D_DIM/32)*(TWO_D/32), 256, 0, stream>>>(w1, w1t, D_DIM, TWO_D);
  cvt_transpose<<<(D_DIM/32)*(D_DIM/32), 256, 0, stream>>>(w2, w2t, D_DIM, D_DIM);

  // GEMM1: M=32768, N=2048, K=1024 -> 1024 blocks
  gemm256<0><<<dim3((BT_DIM/256)*(TWO_D/256)), 512, 0, stream>>>(
      xb, w1t, b1, nullptr, ubf, vbf, D_DIM, TWO_D/256);

  scan_a<<<B_DIM*NCHUNK, 256, 0, stream>>>(vbf, convw, convb, la, sb, hend);
  scan_fix<<<(B_DIM*D_DIM + 255)/256, 256, 0, stream>>>(hend, la, hinit);
  scan_c<<<B_DIM*NCHUNK, 256, 0, stream>>>(vbf, ubf, convw, convb, la, sb, sc, sd, hinit, xb);

  // GEMM2: M=32768, N=1024, K=1024 -> 512 blocks; h (bf16) -> ubf
  gemm256<1><<<dim3((BT_DIM/256)*(D_DIM/256)), 512, 0, stream>>>(
      xb, w2t, b2, x, ubf, nullptr, D_DIM, D_DIM/256);

  ln_kernel<<<BT_DIM, 256, 0, stream>>>(ubf, out, lw, lb);
}